// Round 6
// baseline (3622.621 us; speedup 1.0000x reference)
//
#include <hip/hip_runtime.h>
#include <hip/hip_bf16.h>
#include <math.h>

#define NB 128
#define NR 32
#define EPAD 40    // fA row stride in shorts
#define HPAD 136   // bf16 tile row stride in shorts (272B, 16B-aligned)
#define AGP 132    // LDS fp32 accumulator row stride in floats
#define XPAD 132   // head fp32 row stride in floats

// LDS layout for interaction_fused (bytes):
//   [0      .. 33792)  aggL   fp32 [64][AGP]      (edge accum; node-phase H alias)
//   [33792  .. 51200)  bufA   bf16 [64][HPAD]     (edge H; node XA / x_new bf16)
//   [51200  .. 56320)  fA     bf16 [64][EPAD]
//   [56320  .. 57600)  sD/sRC/sJ/sAt/sIl  5 x 64 x 4B
#define SM_TOTAL 57600

static constexpr float CUTOFF_F    = 10.0f;
static constexpr float RBF_STEP    = 10.0f / 31.0f;
static constexpr float RBF_COEFF   = -4.805f;           // -0.5/(10/31)^2
static constexpr float LOG2_F      = 0.69314718055994531f;
static constexpr float PI_OVER_CUT = 0.314159265358979f;

typedef __attribute__((ext_vector_type(8))) short bf16x8;
typedef __attribute__((ext_vector_type(4))) float f32x4;

__device__ __forceinline__ short f2bs(float x) {
    __hip_bfloat16 h = __float2bfloat16(x);   // RNE
    return *reinterpret_cast<short*>(&h);
}
__device__ __forceinline__ float bs2f(unsigned short u) {
    unsigned int v = ((unsigned int)u) << 16;
    return __uint_as_float(v);
}
__device__ __forceinline__ float ssp_f(float v) {
    return fmaxf(v, 0.0f) + __logf(1.0f + __expf(-fabsf(v))) - LOG2_F;
}
__device__ __forceinline__ float silu_f(float v) {
    return v / (1.0f + __expf(-v));
}

// ---------------------------------------------------------------------------
// Weight prep: dst[b][c][r] = bf16(src[b][r][c])
// ---------------------------------------------------------------------------
__global__ void transpose_cvt(const float* __restrict__ src, short* __restrict__ dst,
                              int R, int C, int total) {
    int t = blockIdx.x * blockDim.x + threadIdx.x;
    if (t >= total) return;
    int rc = R * C;
    int b = t / rc;
    int rem = t - b * rc;
    int c = rem / R;
    int r = rem - c * R;
    dst[t] = f2bs(src[(size_t)b * rc + (size_t)r * C + c]);
}

// ---------------------------------------------------------------------------
// Edge prep: d, rcut, per-atom histogram of idx_i (active only), count.
// ---------------------------------------------------------------------------
__global__ void edge_prep2(const float* __restrict__ pos,
                           const int* __restrict__ idx_i,
                           const int* __restrict__ idx_j,
                           float* __restrict__ d_ij,
                           float* __restrict__ rcut,
                           int* __restrict__ hist,
                           int* __restrict__ count,
                           int E) {
    int e = blockIdx.x * blockDim.x + threadIdx.x;
    if (e >= E) return;
    int a = idx_i[e], b = idx_j[e];
    float dx = pos[a * 3 + 0] - pos[b * 3 + 0];
    float dy = pos[a * 3 + 1] - pos[b * 3 + 1];
    float dz = pos[a * 3 + 2] - pos[b * 3 + 2];
    float d = sqrtf(dx * dx + dy * dy + dz * dz);
    d_ij[e] = d;
    float rc = 0.0f;
    bool act = (d < CUTOFF_F);
    if (act) rc = 0.5f * (cosf(d * PI_OVER_CUT) + 1.0f);
    rcut[e] = rc;
    if (act) {
        atomicAdd(&hist[a], 1);
        atomicAdd(count, 1);
    }
}

// ---------------------------------------------------------------------------
// Single-block exclusive scan of hist[N] -> cursor[N]  (1024 threads).
// ---------------------------------------------------------------------------
__global__ __launch_bounds__(1024) void scan_hist(const int* __restrict__ hist,
                                                  int* __restrict__ cursor, int N) {
    __shared__ int part[1024];
    int t = threadIdx.x;
    int chunk = (N + 1023) / 1024;
    int lo = t * chunk;
    int hi = min(lo + chunk, N);
    int s = 0;
    for (int i = lo; i < hi; i++) s += hist[i];
    part[t] = s;
    __syncthreads();
    for (int d = 1; d < 1024; d <<= 1) {
        int v = (t >= d) ? part[t - d] : 0;
        __syncthreads();
        part[t] += v;
        __syncthreads();
    }
    int run = (t == 0) ? 0 : part[t - 1];
    for (int i = lo; i < hi; i++) {
        cursor[i] = run;
        run += hist[i];
    }
}

// ---------------------------------------------------------------------------
// Scatter active edges into idx_i-grouped order, materializing packed
// per-edge records. After this, cursor[a] == end of atom a's range (rowend).
// ---------------------------------------------------------------------------
__global__ void scatter_sorted2(const float* __restrict__ d_ij,
                                const float* __restrict__ rcut,
                                const int* __restrict__ idx_i,
                                const int* __restrict__ idx_j,
                                const int* __restrict__ edge_attr,
                                int* __restrict__ cursor,
                                float4* __restrict__ edata,
                                int* __restrict__ sIarr, int E) {
    int e = blockIdx.x * blockDim.x + threadIdx.x;
    if (e >= E) return;
    float d = d_ij[e];
    if (d < CUTOFF_F) {
        int i = idx_i[e];
        int p = atomicAdd(&cursor[i], 1);
        float4 v;
        v.x = d;
        v.y = rcut[e];
        v.z = __int_as_float(idx_j[e]);
        v.w = __int_as_float(edge_attr[e]);
        edata[p] = v;
        sIarr[p] = i;
    }
}

// ---------------------------------------------------------------------------
// x = ele_emb[z] + res_emb[z_res]
// ---------------------------------------------------------------------------
__global__ void atom_embed(const int* __restrict__ z,
                           const int* __restrict__ z_res,
                           const float* __restrict__ ele_emb,
                           const float* __restrict__ res_emb,
                           float* __restrict__ x, int N) {
    int t = blockIdx.x * blockDim.x + threadIdx.x;
    if (t >= N * NB) return;
    int n = t >> 7, c = t & 127;
    x[t] = ele_emb[z[n] * NB + c] + res_emb[z_res[n] * NB + c];
}

// ---------------------------------------------------------------------------
// xf(bf16) = in(fp32) @ W  via MFMA. First-iteration in2f.
// ---------------------------------------------------------------------------
__global__ __launch_bounds__(256, 4) void node_in2f_mfma(
    const float* __restrict__ x, const short* __restrict__ WT,
    short* __restrict__ xf, int N) {
    __shared__ __align__(16) short XA[64 * HPAD];
    int a0 = blockIdx.x * 64;
    int t = threadIdx.x;
#pragma unroll
    for (int c = 0; c < 4; c++) {
        int chunk = t + c * 256;
        int row = chunk >> 4;
        int col = (chunk & 15) * 8;
        short v[8];
        if (a0 + row < N) {
            const float* src = x + (size_t)(a0 + row) * NB + col;
            float4 f0 = *(const float4*)src;
            float4 f1 = *(const float4*)(src + 4);
            v[0] = f2bs(f0.x); v[1] = f2bs(f0.y); v[2] = f2bs(f0.z); v[3] = f2bs(f0.w);
            v[4] = f2bs(f1.x); v[5] = f2bs(f1.y); v[6] = f2bs(f1.z); v[7] = f2bs(f1.w);
        } else {
#pragma unroll
            for (int j = 0; j < 8; j++) v[j] = 0;
        }
        *(bf16x8*)&XA[row * HPAD + col] = *(bf16x8*)v;
    }
    __syncthreads();

    int wid = t >> 6, lane = t & 63;
    int quad = lane >> 4, col = lane & 15;
    int mrow = wid * 16 + col;

    f32x4 acc[8] = {};
#pragma unroll
    for (int kt = 0; kt < 4; kt++) {
        bf16x8 a = *(bf16x8*)&XA[mrow * HPAD + kt * 32 + quad * 8];
#pragma unroll
        for (int nt = 0; nt < 8; nt++) {
            bf16x8 b = *(const bf16x8*)&WT[(nt * 16 + col) * NB + kt * 32 + quad * 8];
            acc[nt] = __builtin_amdgcn_mfma_f32_16x16x32_bf16(a, b, acc[nt], 0, 0, 0);
        }
    }
#pragma unroll
    for (int nt = 0; nt < 8; nt++) {
        int n = nt * 16 + col;
#pragma unroll
        for (int r = 0; r < 4; r++) {
            int m = wid * 16 + quad * 4 + r;
            if (a0 + m < N) xf[(size_t)(a0 + m) * NB + n] = f2bs(acc[nt][r]);
        }
    }
}

// ---------------------------------------------------------------------------
// Owner-computes fused interaction: block owns atoms [a0, a0+64) and their
// full sorted edge range. Edge filter MLP (MFMA) + gather + LDS accumulation
// (zero global atomics), then node MLP (f2out) + residual + next-iter in2f,
// all in one kernel. agg never touches global memory.
// ---------------------------------------------------------------------------
__global__ __launch_bounds__(256, 2) void interaction_fused(
    const float4* __restrict__ edata, const int* __restrict__ sIarr,
    const int* __restrict__ rowend,          // post-scatter cursor: end of atom a's range
    const float* __restrict__ edge_emb,
    const short* __restrict__ fW1T, const float* __restrict__ fb1,
    const short* __restrict__ fW2T, const float* __restrict__ fb2,
    const short* __restrict__ oW1T, const float* __restrict__ ob1,
    const short* __restrict__ oW2T, const float* __restrict__ ob2,
    const short* __restrict__ WnT, int has_next,
    const short* __restrict__ xf_in,
    float* __restrict__ x, short* __restrict__ xf_out, int N) {
    __shared__ __align__(16) char smem[SM_TOTAL];
    float* aggL = (float*)smem;                       // [64][AGP] fp32
    short* bufA = (short*)(smem + 33792);             // [64][HPAD] bf16
    short* fA   = (short*)(smem + 51200);             // [64][EPAD] bf16
    float* sD   = (float*)(smem + 56320);
    float* sRC  = sD + 64;
    int*   sJ   = (int*)(sRC + 64);
    int*   sAt  = sJ + 64;
    int*   sIl  = sAt + 64;

    int a0 = blockIdx.x * 64;
    int t = threadIdx.x;
    int wid = t >> 6, lane = t & 63;
    int quad = lane >> 4, col = lane & 15;
    int mrow = wid * 16 + col;
    int e0 = wid * 16 + quad * 4;

    // zero LDS accumulator
    for (int k = t; k < 64 * AGP; k += 256) aggL[k] = 0.0f;

    int sbase = (a0 == 0) ? 0 : rowend[a0 - 1];
    int aend = min(a0 + 63, N - 1);
    int send = rowend[aend];

    const unsigned short* xg = (const unsigned short*)xf_in;
    __syncthreads();

    // ---------------- edge phase ----------------
    for (int et = sbase; et < send; et += 64) {
        int L = send - et;
        if (t < 64) {
            if (t < L) {
                float4 v = edata[et + t];
                sD[t] = v.x;
                sRC[t] = v.y;
                sJ[t] = __float_as_int(v.z);
                sAt[t] = __float_as_int(v.w);
                sIl[t] = sIarr[et + t] - a0;
            } else {
                sD[t] = 1e9f; sRC[t] = 0.0f; sJ[t] = 0; sAt[t] = 0; sIl[t] = 0;
            }
        }
        __syncthreads();

        // early scattered gather of xf rows (latency overlaps MFMA below)
        unsigned short xv[32];
#pragma unroll
        for (int nt = 0; nt < 8; nt++) {
            int n = nt * 16 + col;
#pragma unroll
            for (int r = 0; r < 4; r++)
                xv[nt * 4 + r] = xg[(size_t)sJ[e0 + r] * NB + n];
        }

        // fA: RBF + edge_emb (masked edges give rc=0 downstream; values harmless)
        {
            int e_loc = t >> 2;
            int r0 = (t & 3) * 8;
            float d = sD[e_loc];
            const float* em = edge_emb + sAt[e_loc] * NR + r0;
            short v[8];
#pragma unroll
            for (int j = 0; j < 8; j++) {
                float off = (float)(r0 + j) * RBF_STEP;
                float dd = d - off;
                float ex = (d < CUTOFF_F) ? __expf(RBF_COEFF * dd * dd) : 0.0f;
                v[j] = f2bs(ex + em[j]);
            }
            *(bf16x8*)&fA[e_loc * EPAD + r0] = *(bf16x8*)v;
        }
        __syncthreads();

        // GEMM1: hidden = f_ij @ fW1 (K=32) -> ssp -> bufA
        {
            bf16x8 a1 = *(bf16x8*)&fA[mrow * EPAD + quad * 8];
            f32x4 acc[8];
#pragma unroll
            for (int nt = 0; nt < 8; nt++) {
                bf16x8 b = *(const bf16x8*)&fW1T[(nt * 16 + col) * NR + quad * 8];
                acc[nt] = __builtin_amdgcn_mfma_f32_16x16x32_bf16(a1, b, (f32x4){0.f, 0.f, 0.f, 0.f}, 0, 0, 0);
            }
#pragma unroll
            for (int nt = 0; nt < 8; nt++) {
                int n = nt * 16 + col;
                float bias = fb1[n];
#pragma unroll
                for (int r = 0; r < 4; r++) {
                    int m = wid * 16 + quad * 4 + r;
                    bufA[m * HPAD + n] = f2bs(ssp_f(acc[nt][r] + bias));
                }
            }
        }
        __syncthreads();

        // GEMM2: Wij = hidden @ fW2 (K=128)
        f32x4 acc2[8] = {};
#pragma unroll
        for (int kt = 0; kt < 4; kt++) {
            bf16x8 a = *(bf16x8*)&bufA[mrow * HPAD + kt * 32 + quad * 8];
#pragma unroll
            for (int nt = 0; nt < 8; nt++) {
                bf16x8 b = *(const bf16x8*)&fW2T[(nt * 16 + col) * NB + kt * 32 + quad * 8];
                acc2[nt] = __builtin_amdgcn_mfma_f32_16x16x32_bf16(a, b, acc2[nt], 0, 0, 0);
            }
        }

        // epilogue: merge equal-atom runs, LDS-atomic accumulate
#pragma unroll
        for (int nt = 0; nt < 8; nt++) {
            int n = nt * 16 + col;
            float bias = fb2[n];
            int cur = sIl[e0];
            float accum = 0.0f;
#pragma unroll
            for (int r = 0; r < 4; r++) {
                int el = e0 + r;
                float w = (acc2[nt][r] + bias) * sRC[el];
                float xvf = bs2f(xv[nt * 4 + r]);
                int ii = sIl[el];
                if (ii != cur) {
                    atomicAdd(&aggL[cur * AGP + n], accum);
                    accum = 0.0f;
                    cur = ii;
                }
                accum = fmaf(w, xvf, accum);
            }
            atomicAdd(&aggL[cur * AGP + n], accum);
        }
        __syncthreads();   // protect sIl/sRC/bufA before next tile
    }

    // ---------------- node phase ----------------
    // convert aggL -> bufA (bf16)
    {
        int row = t >> 2, q = t & 3;
        const float* rp = &aggL[row * AGP + q * 32];
        short* wp = &bufA[row * HPAD + q * 32];
#pragma unroll
        for (int k = 0; k < 32; k++) wp[k] = f2bs(rp[k]);
    }
    __syncthreads();
    short* Hn = (short*)smem;   // reuse aggL region as bf16 [64][HPAD]

    // GEMM1: ssp(agg @ oW1 + b1) -> Hn
    {
        f32x4 acc[8] = {};
#pragma unroll
        for (int kt = 0; kt < 4; kt++) {
            bf16x8 a = *(bf16x8*)&bufA[mrow * HPAD + kt * 32 + quad * 8];
#pragma unroll
            for (int nt = 0; nt < 8; nt++) {
                bf16x8 b = *(const bf16x8*)&oW1T[(nt * 16 + col) * NB + kt * 32 + quad * 8];
                acc[nt] = __builtin_amdgcn_mfma_f32_16x16x32_bf16(a, b, acc[nt], 0, 0, 0);
            }
        }
#pragma unroll
        for (int nt = 0; nt < 8; nt++) {
            int n = nt * 16 + col;
            float bias = ob1[n];
#pragma unroll
            for (int r = 0; r < 4; r++) {
                int m = wid * 16 + quad * 4 + r;
                Hn[m * HPAD + n] = f2bs(ssp_f(acc[nt][r] + bias));
            }
        }
    }
    __syncthreads();

    // GEMM2: v = Hn @ oW2 + b2 ; x += v ; x_new bf16 -> bufA
    {
        f32x4 acc[8] = {};
#pragma unroll
        for (int kt = 0; kt < 4; kt++) {
            bf16x8 a = *(bf16x8*)&Hn[mrow * HPAD + kt * 32 + quad * 8];
#pragma unroll
            for (int nt = 0; nt < 8; nt++) {
                bf16x8 b = *(const bf16x8*)&oW2T[(nt * 16 + col) * NB + kt * 32 + quad * 8];
                acc[nt] = __builtin_amdgcn_mfma_f32_16x16x32_bf16(a, b, acc[nt], 0, 0, 0);
            }
        }
#pragma unroll
        for (int nt = 0; nt < 8; nt++) {
            int n = nt * 16 + col;
            float bias = ob2[n];
#pragma unroll
            for (int r = 0; r < 4; r++) {
                int m = wid * 16 + quad * 4 + r;
                float xn = 0.0f;
                if (a0 + m < N) {
                    size_t o = (size_t)(a0 + m) * NB + n;
                    xn = x[o] + acc[nt][r] + bias;
                    x[o] = xn;
                }
                bufA[m * HPAD + n] = f2bs(xn);
            }
        }
    }
    __syncthreads();

    // GEMM3: xf_next = x_new @ Wn (skip on last interaction)
    if (has_next) {
        f32x4 acc[8] = {};
#pragma unroll
        for (int kt = 0; kt < 4; kt++) {
            bf16x8 a = *(bf16x8*)&bufA[mrow * HPAD + kt * 32 + quad * 8];
#pragma unroll
            for (int nt = 0; nt < 8; nt++) {
                bf16x8 b = *(const bf16x8*)&WnT[(nt * 16 + col) * NB + kt * 32 + quad * 8];
                acc[nt] = __builtin_amdgcn_mfma_f32_16x16x32_bf16(a, b, acc[nt], 0, 0, 0);
            }
        }
#pragma unroll
        for (int nt = 0; nt < 8; nt++) {
            int n = nt * 16 + col;
#pragma unroll
            for (int r = 0; r < 4; r++) {
                int m = wid * 16 + quad * 4 + r;
                if (a0 + m < N) xf_out[(size_t)(a0 + m) * NB + n] = f2bs(acc[nt][r]);
            }
        }
    }
}

// ---------------------------------------------------------------------------
// Head (MFMA): L2-normalize, silu -> W1 -> silu -> W2, segment-sum by batch.
// ---------------------------------------------------------------------------
__global__ __launch_bounds__(256, 4) void head_mfma(
    const float* __restrict__ x, const int* __restrict__ batch,
    const short* __restrict__ W1T, const float* __restrict__ b1,
    const float* __restrict__ W2,
    float* __restrict__ out, int N) {
    __shared__ float X[64 * XPAD];
    __shared__ __align__(16) short XA[64 * HPAD];
    __shared__ float invn[64];
    __shared__ int sbat[64];
    __shared__ float rowval[64];

    int a0 = blockIdx.x * 64;
    int t = threadIdx.x;

#pragma unroll
    for (int c = 0; c < 8; c++) {
        int chunk = t + c * 256;
        int row = chunk >> 5;
        int col4 = (chunk & 31) * 4;
        float4 v;
        if (a0 + row < N) v = *(const float4*)(x + (size_t)(a0 + row) * NB + col4);
        else v = (float4){0.f, 0.f, 0.f, 0.f};
        *(float4*)&X[row * XPAD + col4] = v;
    }
    if (t < 64) sbat[t] = (a0 + t < N) ? batch[a0 + t] : -1;
    __syncthreads();

    {
        int row = t >> 2, q = t & 3;
        const float* rp = &X[row * XPAD + q * 32];
        float s = 0.0f;
#pragma unroll
        for (int k4 = 0; k4 < 8; k4++) {
            float4 v = *(const float4*)(rp + k4 * 4);
            s += v.x * v.x + v.y * v.y + v.z * v.z + v.w * v.w;
        }
        s += __shfl_xor(s, 1);
        s += __shfl_xor(s, 2);
        if (q == 0) invn[row] = 1.0f / fmaxf(sqrtf(s), 1e-12f);
    }
    __syncthreads();

    {
        int row = t >> 2, q = t & 3;
        float iv = invn[row];
        const float* rp = &X[row * XPAD + q * 32];
        short* wp = &XA[row * HPAD + q * 32];
#pragma unroll
        for (int k = 0; k < 32; k++) wp[k] = f2bs(silu_f(rp[k] * iv));
    }
    __syncthreads();

    int wid = t >> 6, lane = t & 63;
    int quad = lane >> 4, col = lane & 15;
    int mrow = wid * 16 + col;

    f32x4 acc[8] = {};
#pragma unroll
    for (int kt = 0; kt < 4; kt++) {
        bf16x8 a = *(bf16x8*)&XA[mrow * HPAD + kt * 32 + quad * 8];
#pragma unroll
        for (int nt = 0; nt < 8; nt++) {
            bf16x8 b = *(const bf16x8*)&W1T[(nt * 16 + col) * NB + kt * 32 + quad * 8];
            acc[nt] = __builtin_amdgcn_mfma_f32_16x16x32_bf16(a, b, acc[nt], 0, 0, 0);
        }
    }
    float partial[4] = {0.f, 0.f, 0.f, 0.f};
#pragma unroll
    for (int nt = 0; nt < 8; nt++) {
        int n = nt * 16 + col;
        float bias = b1[n];
        float w2 = W2[n];
#pragma unroll
        for (int r = 0; r < 4; r++) partial[r] += silu_f(acc[nt][r] + bias) * w2;
    }
#pragma unroll
    for (int r = 0; r < 4; r++) {
#pragma unroll
        for (int d = 1; d < 16; d <<= 1) partial[r] += __shfl_xor(partial[r], d);
    }
    if (col == 0) {
#pragma unroll
        for (int r = 0; r < 4; r++) rowval[wid * 16 + quad * 4 + r] = partial[r];
    }
    __syncthreads();

    if (t < 64) {
        int b = sbat[t];
        bool valid = (b >= 0);
        bool headf = valid && (t == 0 || sbat[t - 1] != b);
        if (headf) {
            float s = 0.0f;
            int rr = t;
            while (rr < 64 && sbat[rr] == b) { s += rowval[rr]; rr++; }
            atomicAdd(&out[b], s);
        }
    }
}

// ---------------------------------------------------------------------------
extern "C" void kernel_launch(void* const* d_in, const int* in_sizes, int n_in,
                              void* d_out, int out_size, void* d_ws, size_t ws_size,
                              hipStream_t stream) {
    const int*   z        = (const int*)d_in[0];
    const int*   z_res    = (const int*)d_in[1];
    const float* pos      = (const float*)d_in[2];
    const int*   idx_i    = (const int*)d_in[3];
    const int*   idx_j    = (const int*)d_in[4];
    const int*   edge_attr= (const int*)d_in[5];
    const int*   batch    = (const int*)d_in[6];
    const float* ele_emb  = (const float*)d_in[7];
    const float* res_emb  = (const float*)d_in[8];
    const float* edge_emb = (const float*)d_in[9];
    const float* in2f_W   = (const float*)d_in[10];
    const float* filt_W1  = (const float*)d_in[11];
    const float* filt_b1  = (const float*)d_in[12];
    const float* filt_W2  = (const float*)d_in[13];
    const float* filt_b2  = (const float*)d_in[14];
    const float* f2out_W1 = (const float*)d_in[15];
    const float* f2out_b1 = (const float*)d_in[16];
    const float* f2out_W2 = (const float*)d_in[17];
    const float* f2out_b2 = (const float*)d_in[18];
    const float* head_W1  = (const float*)d_in[19];
    const float* head_b1  = (const float*)d_in[20];
    const float* head_W2  = (const float*)d_in[21];

    const int N = in_sizes[0];
    const int E = in_sizes[3];

    char* p = (char*)d_ws;
    size_t off = 0;
    auto carve = [&](size_t bytes) -> void* {
        void* q = p + off;
        off = (off + bytes + 255) & ~(size_t)255;
        return q;
    };
    float*  d_d      = (float*)carve((size_t)E * 4);
    float*  d_rc     = (float*)carve((size_t)E * 4);
    float4* edata    = (float4*)carve((size_t)E * 16);
    int*    sIarr    = (int*)carve((size_t)E * 4);
    int*    hist     = (int*)carve((size_t)N * 4);
    int*    cursor   = (int*)carve((size_t)N * 4);
    int*    count    = (int*)carve(256);
    float*  x_buf    = (float*)carve((size_t)N * NB * 4);
    short*  xf_buf   = (short*)carve((size_t)N * NB * 2);
    short*  in2f_WT  = (short*)carve((size_t)6 * NB * NB * 2);
    short*  fW1T     = (short*)carve((size_t)6 * NR * NB * 2);
    short*  fW2T     = (short*)carve((size_t)6 * NB * NB * 2);
    short*  oW1T     = (short*)carve((size_t)6 * NB * NB * 2);
    short*  oW2T     = (short*)carve((size_t)6 * NB * NB * 2);
    short*  hW1T     = (short*)carve((size_t)NB * NB * 2);
    (void)ws_size;

    // weight prep (bf16 transposed)
    {
        int tot = 6 * NB * NB;
        transpose_cvt<<<(tot + 255) / 256, 256, 0, stream>>>(in2f_W, in2f_WT, NB, NB, tot);
        transpose_cvt<<<(tot + 255) / 256, 256, 0, stream>>>(filt_W2, fW2T, NB, NB, tot);
        transpose_cvt<<<(tot + 255) / 256, 256, 0, stream>>>(f2out_W1, oW1T, NB, NB, tot);
        transpose_cvt<<<(tot + 255) / 256, 256, 0, stream>>>(f2out_W2, oW2T, NB, NB, tot);
        int tot1 = 6 * NR * NB;
        transpose_cvt<<<(tot1 + 255) / 256, 256, 0, stream>>>(filt_W1, fW1T, NR, NB, tot1);
        int tot2 = NB * NB;
        transpose_cvt<<<(tot2 + 255) / 256, 256, 0, stream>>>(head_W1, hW1T, NB, NB, tot2);
    }

    // edge prep + idx_i-grouped sort with packed records
    hipMemsetAsync(hist, 0, (size_t)N * 4, stream);
    hipMemsetAsync(count, 0, sizeof(int), stream);
    edge_prep2<<<(E + 255) / 256, 256, 0, stream>>>(pos, idx_i, idx_j, d_d, d_rc,
                                                    hist, count, E);
    scan_hist<<<1, 1024, 0, stream>>>(hist, cursor, N);
    scatter_sorted2<<<(E + 255) / 256, 256, 0, stream>>>(d_d, d_rc, idx_i, idx_j,
                                                         edge_attr, cursor, edata,
                                                         sIarr, E);
    // cursor[a] is now the END of atom a's sorted-edge range.

    atom_embed<<<(N * NB + 255) / 256, 256, 0, stream>>>(z, z_res, ele_emb, res_emb, x_buf, N);

    int nblk_atom64 = (N + 63) / 64;

    node_in2f_mfma<<<nblk_atom64, 256, 0, stream>>>(x_buf, in2f_WT, xf_buf, N);
    for (int i = 0; i < 6; i++) {
        int has_next = (i < 5) ? 1 : 0;
        interaction_fused<<<nblk_atom64, 256, 0, stream>>>(
            edata, sIarr, cursor, edge_emb,
            fW1T + (size_t)i * NR * NB, filt_b1 + (size_t)i * NB,
            fW2T + (size_t)i * NB * NB, filt_b2 + (size_t)i * NB,
            oW1T + (size_t)i * NB * NB, f2out_b1 + (size_t)i * NB,
            oW2T + (size_t)i * NB * NB, f2out_b2 + (size_t)i * NB,
            in2f_WT + (size_t)((i + 1) % 6) * NB * NB, has_next,
            xf_buf, x_buf, xf_buf, N);
    }

    hipMemsetAsync(d_out, 0, (size_t)out_size * sizeof(float), stream);
    head_mfma<<<nblk_atom64, 256, 0, stream>>>(x_buf, batch, hW1T, head_b1, head_W2,
                                               (float*)d_out, N);
}